// Round 14
// baseline (233.178 us; speedup 1.0000x reference)
//
#include <hip/hip_runtime.h>
#include <hip/hip_bf16.h>

// LightGCN propagation: x = concat(user,item) [150000,64] f32;
// acc = x; 3x { x = A@x (COO spmm, E=1.2M); acc += x }; out = acc/4.
//
// Round 14 = round 13 with S1_CHUNK 2048->1024: the scatter role had only
// 586 blocks carrying the serial rank->reserve->scatter chain (s1=44us,
// VALUBusy 3%, occ 57% -> latency-bound); 1172 blocks halves per-thread
// serial work.
//  1) memset cursor1 (1172 x 4B)
//  2) s1_convert (role-split grid): LDS-rank edges per bucket (row>>7),
//     reserve via atomicAdd(cursor1[b]), write 8B records tmp[b*BCAP+pos]
//     (UNSTAGED: at shift 7 bucket-runs ~1.75 rec < 32B sector; round 12
//     proved staging regresses); + x0 fp32->fp16 staging.
//  3-5) spmm_bucket x3: block = bucket (128 rows), 512 thr, LDS acc
//     128x65 INT via native ds_add_u32, 4x-unrolled gathers.
//     SCALE=2^20 fixed point: quant 5e-7/term vs 2.4e-4 fp16 floor.
//     Layer 3 fuses out = 0.25*(x0h+x1+x2+acc).
//
// POST-MORTEM LOG:
//  - prior session r6: nt-STORES on Xout REGRESSED spmm: evicts L2 lines
//    next layer's gathers need.
//  - round 2: per-edge GLOBAL atomicAdd(+return) = 331us. NEVER.
//  - round 5: FP32 LDS atomicAdd = 435us/layer (CAS retry). INT LDS
//    atomicAdd is native ds_add — round 11 proved <=42us/layer.
//  - round 6: degree-sorted slots REGRESSED: spmm is GATHER-bound.
//  - round 9: packed cw + nt-loads: FETCH -8MB, duration UNCHANGED.
//  - round 12: staged s1 at shift 7 REGRESSED 44->53us (runs < sector).
//  - round 13: spmm 4x unroll NULL (218.3->218.9): spmm_bucket is at its
//    compulsory-traffic floor (~100MB/layer = per-XCD duplication of X;
//    cache-blocking cannot reduce it). spmm ~42us/layer is structural.
//  - budget: fill 41 (harness) + s1 44 + spmm 128 + ~5 = 219. s1 is the
//    only component clearly above floor -> this round's lever.

#define EMB 64
#define BUCKET_SHIFT 7
#define BROWS (1 << BUCKET_SHIFT)    // 128 rows per bucket
#define LROW 65                      // LDS row stride (65 = 1 mod 32)
#define NBUCK_PAD 1184
#define S1_CHUNK 1024
#define BCAP 1408                    // Poisson(1024): +12 sigma headroom
#define ACC_SCALE 1048576.0f         // 2^20 fixed-point scale
#define ACC_INV (1.0f / 1048576.0f)

typedef _Float16 h8 __attribute__((ext_vector_type(8)));
typedef float f4 __attribute__((ext_vector_type(4)));

union H8U { h8 v; _Float16 e[8]; };

// ---- fused scatter1 + fp32->fp16 convert (role-split grid) ----
__global__ void s1_convert(const int* __restrict__ row, const int* __restrict__ col,
                           const float* __restrict__ w, int* __restrict__ cursor1,
                           int2* __restrict__ tmp,
                           const float* __restrict__ ue, const float* __restrict__ ie,
                           h8* __restrict__ X0h, int nu_elems, int total8,
                           int E, int s1Blocks) {
    int t = threadIdx.x;
    if ((int)blockIdx.x < s1Blocks) {
        __shared__ int lcount[NBUCK_PAD];
        __shared__ int lbase[NBUCK_PAD];
        int c0 = blockIdx.x * S1_CHUNK;
        for (int i = t; i < NBUCK_PAD; i += 512) lcount[i] = 0;
        __syncthreads();
        int pkc[S1_CHUNK / 512];   // (b<<12)|rank
        int cc[S1_CHUNK / 512];
        int rr[S1_CHUNK / 512];
        float ww[S1_CHUNK / 512];
        #pragma unroll
        for (int i = 0; i < S1_CHUNK / 512; i++) {
            int e = c0 + i * 512 + t;
            pkc[i] = -1;
            if (e < E) {
                int r = row[e];
                int b = r >> BUCKET_SHIFT;
                int rank = atomicAdd(&lcount[b], 1);
                pkc[i] = (b << 12) | rank;
                cc[i] = col[e];
                rr[i] = r & (BROWS - 1);
                ww[i] = w[e];
            }
        }
        __syncthreads();
        for (int i = t; i < NBUCK_PAD; i += 512) {
            int c = lcount[i];
            if (c) lbase[i] = atomicAdd(&cursor1[i], c);
        }
        __syncthreads();
        #pragma unroll
        for (int i = 0; i < S1_CHUNK / 512; i++) {
            if (pkc[i] >= 0) {
                int b = pkc[i] >> 12;
                int pos = lbase[b] + (pkc[i] & 4095);
                if (pos < BCAP)   // overflow guard (never triggers at +12 sigma)
                    tmp[(size_t)b * BCAP + pos] =
                        make_int2((cc[i] << BUCKET_SHIFT) | rr[i], __float_as_int(ww[i]));
            }
        }
    } else {
        int g = (blockIdx.x - s1Blocks) * 512 + t;
        if (g >= total8) return;
        int base = g << 3;
        const f4* src = (const f4*)((base < nu_elems) ? (ue + base)
                                                      : (ie + (base - nu_elems)));
        f4 a = src[0], b = src[1];
        h8 o;
        o[0] = (_Float16)a.x; o[1] = (_Float16)a.y; o[2] = (_Float16)a.z; o[3] = (_Float16)a.w;
        o[4] = (_Float16)b.x; o[5] = (_Float16)b.y; o[6] = (_Float16)b.z; o[7] = (_Float16)b.w;
        X0h[g] = o;
    }
}

// ---- spmm: bucket-per-block, INT LDS accumulate, 4x-unrolled gathers ----
// LAST fuses out = 0.25*(x0h + x1 + x2 + acc)
template <bool LAST>
__global__ __launch_bounds__(512) void spmm_bucket(
        const int* __restrict__ cursor1, const int2* __restrict__ tmp,
        const h8* __restrict__ Xin, h8* __restrict__ Xout,
        const h8* __restrict__ X0, const h8* __restrict__ X1,
        float* __restrict__ out, int nrows) {
    __shared__ int acc[BROWS * LROW];   // 128 x 65 int = 33.3 KB
    int t = threadIdx.x;
    int b = blockIdx.x;

    int4* az = (int4*)acc;
    for (int i = t; i < BROWS * LROW / 4; i += 512) az[i] = make_int4(0, 0, 0, 0);
    __syncthreads();

    int num = cursor1[b];
    if (num > BCAP) num = BCAP;
    const int2* ebase = tmp + (size_t)b * BCAP;

    int g = t >> 3;      // 0..63: one edge per 8-lane group
    int l8 = t & 7;      // 16B chunk of the source row

    int e = g;
    for (; e + 192 < num; e += 256) {
        int2 r0 = ebase[e];
        int2 r1 = ebase[e + 64];
        int2 r2 = ebase[e + 128];
        int2 r3 = ebase[e + 192];
        H8U v0, v1, v2, v3;
        v0.v = Xin[((r0.x >> BUCKET_SHIFT) << 3) + l8];
        v1.v = Xin[((r1.x >> BUCKET_SHIFT) << 3) + l8];
        v2.v = Xin[((r2.x >> BUCKET_SHIFT) << 3) + l8];
        v3.v = Xin[((r3.x >> BUCKET_SHIFT) << 3) + l8];
        float w0 = __int_as_float(r0.y) * ACC_SCALE;
        float w1 = __int_as_float(r1.y) * ACC_SCALE;
        float w2 = __int_as_float(r2.y) * ACC_SCALE;
        float w3 = __int_as_float(r3.y) * ACC_SCALE;
        int* d0 = &acc[(r0.x & (BROWS - 1)) * LROW + l8 * 8];
        int* d1 = &acc[(r1.x & (BROWS - 1)) * LROW + l8 * 8];
        int* d2 = &acc[(r2.x & (BROWS - 1)) * LROW + l8 * 8];
        int* d3 = &acc[(r3.x & (BROWS - 1)) * LROW + l8 * 8];
        #pragma unroll
        for (int k = 0; k < 8; k++) atomicAdd(&d0[k], __float2int_rn(w0 * (float)v0.e[k]));
        #pragma unroll
        for (int k = 0; k < 8; k++) atomicAdd(&d1[k], __float2int_rn(w1 * (float)v1.e[k]));
        #pragma unroll
        for (int k = 0; k < 8; k++) atomicAdd(&d2[k], __float2int_rn(w2 * (float)v2.e[k]));
        #pragma unroll
        for (int k = 0; k < 8; k++) atomicAdd(&d3[k], __float2int_rn(w3 * (float)v3.e[k]));
    }
    for (; e + 64 < num; e += 128) {
        int2 r0 = ebase[e];
        int2 r1 = ebase[e + 64];
        H8U v0, v1;
        v0.v = Xin[((r0.x >> BUCKET_SHIFT) << 3) + l8];
        v1.v = Xin[((r1.x >> BUCKET_SHIFT) << 3) + l8];
        float w0 = __int_as_float(r0.y) * ACC_SCALE;
        float w1 = __int_as_float(r1.y) * ACC_SCALE;
        int* d0 = &acc[(r0.x & (BROWS - 1)) * LROW + l8 * 8];
        int* d1 = &acc[(r1.x & (BROWS - 1)) * LROW + l8 * 8];
        #pragma unroll
        for (int k = 0; k < 8; k++) atomicAdd(&d0[k], __float2int_rn(w0 * (float)v0.e[k]));
        #pragma unroll
        for (int k = 0; k < 8; k++) atomicAdd(&d1[k], __float2int_rn(w1 * (float)v1.e[k]));
    }
    for (; e < num; e += 64) {
        int2 r0 = ebase[e];
        H8U v0;
        v0.v = Xin[((r0.x >> BUCKET_SHIFT) << 3) + l8];
        float w0 = __int_as_float(r0.y) * ACC_SCALE;
        int* d0 = &acc[(r0.x & (BROWS - 1)) * LROW + l8 * 8];
        #pragma unroll
        for (int k = 0; k < 8; k++) atomicAdd(&d0[k], __float2int_rn(w0 * (float)v0.e[k]));
    }
    __syncthreads();

    // epilogue: 128 rows x 8 chunks of 8 values
    int rowbase = b << BUCKET_SHIFT;
    int rows_here = nrows - rowbase;
    if (rows_here > BROWS) rows_here = BROWS;
    for (int i = t; i < rows_here * 8; i += 512) {
        int r = i >> 3, c8 = i & 7;
        int rowid = rowbase + r;
        const int* src = &acc[r * LROW + c8 * 8];
        if (LAST) {
            h8 x0 = X0[(rowid << 3) + c8];
            h8 v1 = X1[(rowid << 3) + c8];
            h8 v2 = Xin[(rowid << 3) + c8];
            int base = (rowid << 6) + (c8 << 3);
            f4 o0, o1;
            o0.x = 0.25f * ((float)x0[0] + (float)v1[0] + (float)v2[0] + (float)src[0] * ACC_INV);
            o0.y = 0.25f * ((float)x0[1] + (float)v1[1] + (float)v2[1] + (float)src[1] * ACC_INV);
            o0.z = 0.25f * ((float)x0[2] + (float)v1[2] + (float)v2[2] + (float)src[2] * ACC_INV);
            o0.w = 0.25f * ((float)x0[3] + (float)v1[3] + (float)v2[3] + (float)src[3] * ACC_INV);
            o1.x = 0.25f * ((float)x0[4] + (float)v1[4] + (float)v2[4] + (float)src[4] * ACC_INV);
            o1.y = 0.25f * ((float)x0[5] + (float)v1[5] + (float)v2[5] + (float)src[5] * ACC_INV);
            o1.z = 0.25f * ((float)x0[6] + (float)v1[6] + (float)v2[6] + (float)src[6] * ACC_INV);
            o1.w = 0.25f * ((float)x0[7] + (float)v1[7] + (float)v2[7] + (float)src[7] * ACC_INV);
            f4* dst = (f4*)(out + base);
            dst[0] = o0;
            dst[1] = o1;
        } else {
            h8 o;
            #pragma unroll
            for (int k = 0; k < 8; k++) o[k] = (_Float16)((float)src[k] * ACC_INV);
            Xout[(rowid << 3) + c8] = o;
        }
    }
}

extern "C" void kernel_launch(void* const* d_in, const int* in_sizes, int n_in,
                              void* d_out, int out_size, void* d_ws, size_t ws_size,
                              hipStream_t stream) {
    const int* edge_row = (const int*)d_in[0];
    const int* edge_col = (const int*)d_in[1];
    const float* edge_w = (const float*)d_in[2];
    const float* user_emb = (const float*)d_in[3];
    const float* item_emb = (const float*)d_in[4];

    const int E = in_sizes[0];
    const int nu_elems = in_sizes[3];
    const int ni_elems = in_sizes[4];
    const int total = nu_elems + ni_elems;
    const int N = total / EMB;                           // 150000
    const int NBUCK = (N + BROWS - 1) >> BUCKET_SHIFT;   // 1172

    size_t off = 0;
    auto carve = [&](size_t bytes) {
        void* p = (char*)d_ws + off;
        off += (bytes + 255) & ~(size_t)255;
        return p;
    };
    h8*    X0h     = (h8*)carve((size_t)total * 2);
    h8*    X1h     = (h8*)carve((size_t)total * 2);
    h8*    X2h     = (h8*)carve((size_t)total * 2);
    int*   cursor1 = (int*)carve((size_t)NBUCK * 4);
    int2*  tmp     = (int2*)carve((size_t)NBUCK * BCAP * 8);
    (void)ws_size;

    float* out = (float*)d_out;

    const int total8 = total / 8;
    const int s1Blocks = (E + S1_CHUNK - 1) / S1_CHUNK;
    const int convBlocks = (total8 + 511) / 512;

    hipMemsetAsync(cursor1, 0, (size_t)NBUCK * 4, stream);
    s1_convert<<<s1Blocks + convBlocks, 512, 0, stream>>>(
        edge_row, edge_col, edge_w, cursor1, tmp,
        user_emb, item_emb, X0h, nu_elems, total8, E, s1Blocks);

    spmm_bucket<false><<<NBUCK, 512, 0, stream>>>(cursor1, tmp,
                                                  X0h, X1h, nullptr, nullptr,
                                                  nullptr, N);
    spmm_bucket<false><<<NBUCK, 512, 0, stream>>>(cursor1, tmp,
                                                  X1h, X2h, nullptr, nullptr,
                                                  nullptr, N);
    spmm_bucket<true><<<NBUCK, 512, 0, stream>>>(cursor1, tmp,
                                                 X2h, nullptr, X0h, X1h,
                                                 out, N);
}

// Round 15
// 212.603 us; speedup vs baseline: 1.0968x; 1.0968x over previous
//
#include <hip/hip_runtime.h>
#include <hip/hip_bf16.h>

// LightGCN propagation: x = concat(user,item) [150000,64] f32;
// acc = x; 3x { x = A@x (COO spmm, E=1.2M); acc += x }; out = acc/4.
//
// Round 15 = round 7 (verified best 214.1us) + s1 at 1024 threads/block
// (S1_CHUNK stays 2048 -> 2 records/thread, serial 4-phase chain halved;
// block count and per-block 320-counter overhead unchanged — the exact
// inverse of round 14's failed lever).
//  1) memset cursor1 (293 x 4B)
//  2) s1_convert (role-split grid, 1024 thr): LDS-rank edges per bucket
//     (row>>9), reserve via atomicAdd(cursor1[b]); records sorted
//     bucket-contiguously into LDS staging (scan of 320 counters), then
//     written out coalesced (runs ~7 records > 32B sector -> coalescing
//     works at shift 9). + x0 fp32->fp16 staging.
//  3) scatter2: one 1024-thr block per 512-row bucket; rank-atomics
//     (register-cached), LDS scan -> rbeg/rend; placement into LDS
//     staged[BCAP], then cw[base+p]=staged[p] fully coalesced.
//  4-6) spmm x3: GROUP-PER-ROW, 8 rows/wave, lane=16B chunk, 4x-unrolled
//     edges. Layer 3 fuses out = 0.25*(x0h+x1+x2+acc).
//
// POST-MORTEM LOG:
//  - prior session r6: nt-STORES on Xout REGRESSED spmm: evicts L2 lines
//    next layer's gathers need.
//  - round 2: per-edge GLOBAL atomicAdd(+return) = 331us. NEVER.
//  - round 5: FP32 LDS atomicAdd = 435us/layer (CAS retry loop).
//  - round 6: degree-sorted slots REGRESSED: spmm is GATHER-bound
//    (X=19.2MB vs 4MB/XCD L2, ~97MB/layer compulsory per-XCD traffic).
//  - round 9: packed cw + nt-loads: spmm FETCH -8MB, duration UNCHANGED
//    -> gather floor is traffic-service, not BW or record size.
//  - round 10: quarter-split scatter2 +8: scan amplification.
//  - round 12: staged s1 at shift 7 REGRESSED (runs ~1.75 rec < 32B
//    sector). Staging pays only at shift 9 (runs ~7).
//  - round 13: spmm 4x unroll NULL -> spmm at compulsory floor ~40us.
//  - round 14: S1_CHUNK 2048->1024 REGRESSED s1 44->58: per-block
//    counter-init/scan/reserve overhead is chunk-independent; s1 cost
//    scales with blocks x NBUCK_PAD, NOT records/thread.
//  - round 11 branch (bucket-int-LDS spmm, no scatter2): 218.3 plateau.

#define EMB 64
#define BUCKET_SHIFT 9
#define BROWS (1 << BUCKET_SHIFT)    // 512 rows per bucket
#define NBUCK_PAD 320
#define S1_CHUNK 2048
#define BCAP 4608
#define S2_CAP 5
#define SPMM_BLOCKS 2048

typedef _Float16 h8 __attribute__((ext_vector_type(8)));
typedef _Float16 h2v __attribute__((ext_vector_type(2)));
typedef float f2v __attribute__((ext_vector_type(2)));
typedef float f4 __attribute__((ext_vector_type(4)));
typedef int i2v __attribute__((ext_vector_type(2)));

union H8U { h8 v; h2v p[4]; };

// ---- fused scatter1 + fp32->fp16 convert (role-split grid, 1024 thr) ----
// Records staged bucket-contiguously in LDS, written out coalesced.
__global__ void s1_convert(const int* __restrict__ row, const int* __restrict__ col,
                           const float* __restrict__ w, int* __restrict__ cursor1,
                           int2* __restrict__ tmp,
                           const float* __restrict__ ue, const float* __restrict__ ie,
                           h8* __restrict__ X0h, int nu_elems, int total8,
                           int E, int s1Blocks) {
    int t = threadIdx.x;
    if ((int)blockIdx.x < s1Blocks) {
        __shared__ int lcount[NBUCK_PAD];
        __shared__ int lbase[NBUCK_PAD];
        __shared__ int lexcl[NBUCK_PAD];
        __shared__ int2 staged[S1_CHUNK];   // 16 KB
        __shared__ short sbkt[S1_CHUNK];    // 4 KB
        __shared__ int swS[16];
        int c0 = blockIdx.x * S1_CHUNK;
        int chunk_valid = E - c0;
        if (chunk_valid > S1_CHUNK) chunk_valid = S1_CHUNK;
        if (t < NBUCK_PAD) lcount[t] = 0;
        __syncthreads();
        int pkc[S1_CHUNK / 1024];   // (b<<12)|rank
        int cc[S1_CHUNK / 1024];
        int rr[S1_CHUNK / 1024];
        float ww[S1_CHUNK / 1024];
        #pragma unroll
        for (int i = 0; i < S1_CHUNK / 1024; i++) {
            int e = c0 + i * 1024 + t;
            pkc[i] = -1;
            if (e < E) {
                int r = row[e];
                int b = r >> BUCKET_SHIFT;
                int rank = atomicAdd(&lcount[b], 1);
                pkc[i] = (b << 12) | rank;
                cc[i] = col[e];
                rr[i] = r & (BROWS - 1);
                ww[i] = w[e];
            }
        }
        __syncthreads();
        // global reservation + local exclusive scan of 320 bucket counts
        int lane = t & 63, wave = t >> 6;
        int v = (t < NBUCK_PAD) ? lcount[t] : 0;
        if (t < NBUCK_PAD && v) lbase[t] = atomicAdd(&cursor1[t], v);
        int s = v;
        #pragma unroll
        for (int off = 1; off < 64; off <<= 1) {
            int tt = __shfl_up(s, off, 64);
            if (lane >= off) s += tt;
        }
        if (lane == 63) swS[wave] = s;
        __syncthreads();
        {
            int woff = 0;
            for (int wv_ = 0; wv_ < wave; wv_++) woff += swS[wv_];
            if (t < NBUCK_PAD) lexcl[t] = woff + s - v;
        }
        __syncthreads();
        // place bucket-sorted into LDS staging
        #pragma unroll
        for (int i = 0; i < S1_CHUNK / 1024; i++) {
            if (pkc[i] >= 0) {
                int b = pkc[i] >> 12;
                int si = lexcl[b] + (pkc[i] & 4095);
                staged[si] = make_int2((cc[i] << BUCKET_SHIFT) | rr[i],
                                       __float_as_int(ww[i]));
                sbkt[si] = (short)b;
            }
        }
        __syncthreads();
        // coalesced write-out: consecutive i in a bucket-run -> consecutive tmp
        for (int i = t; i < chunk_valid; i += 1024) {
            int b = sbkt[i];
            int pos = lbase[b] + (i - lexcl[b]);
            if (pos < BCAP)   // overflow guard (never triggers at +8 sigma)
                tmp[(size_t)b * BCAP + pos] = staged[i];
        }
    } else {
        int g = (blockIdx.x - s1Blocks) * 1024 + t;
        if (g >= total8) return;
        int base = g << 3;
        const f4* src = (const f4*)((base < nu_elems) ? (ue + base)
                                                      : (ie + (base - nu_elems)));
        f4 a = src[0], b = src[1];
        h8 o;
        o[0] = (_Float16)a.x; o[1] = (_Float16)a.y; o[2] = (_Float16)a.z; o[3] = (_Float16)a.w;
        o[4] = (_Float16)b.x; o[5] = (_Float16)b.y; o[6] = (_Float16)b.z; o[7] = (_Float16)b.w;
        X0h[g] = o;
    }
}

// ---- scatter2: rank + scan + LDS-staged place + coalesced copy-out ----
__global__ void scatter2(const int* __restrict__ cursor1, const int2* __restrict__ tmp,
                         int2* __restrict__ cw, int* __restrict__ rbeg,
                         int* __restrict__ rend, int nrows) {
    __shared__ int cnt[BROWS];
    __shared__ int wS[16];
    __shared__ int2 staged[BCAP];   // 36.8 KB
    int t = threadIdx.x;
    int j = blockIdx.x;
    int rowbase = j << BUCKET_SHIFT;
    int rows_here = nrows - rowbase;
    if (rows_here > BROWS) rows_here = BROWS;
    int num = cursor1[j];
    if (num > BCAP) num = BCAP;
    int base = j * BCAP;
    int iters = (num + 1023) >> 10;   // <= 5 since BCAP=4608

    if (t < BROWS) cnt[t] = 0;
    __syncthreads();

    int pkc[S2_CAP];
    int rk[S2_CAP];
    int wv[S2_CAP];
    for (int i = 0; i < iters; i++) {
        int p = i * 1024 + t;
        pkc[i] = -1;
        if (p < num) {
            int2 rec = tmp[base + p];
            pkc[i] = rec.x;
            wv[i] = rec.y;
            rk[i] = atomicAdd(&cnt[rec.x & (BROWS - 1)], 1);
        }
    }
    __syncthreads();

    int lane = t & 63;
    int wave = t >> 6;
    int v = 0, s = 0;
    if (t < BROWS) {
        v = cnt[t];
        s = v;
        #pragma unroll
        for (int off = 1; off < 64; off <<= 1) {
            int tt = __shfl_up(s, off, 64);
            if (lane >= off) s += tt;
        }
        if (lane == 63) wS[wave] = s;
    }
    __syncthreads();
    int excl = 0;
    if (t < BROWS) {
        int woff = 0;
        for (int w = 0; w < wave; w++) woff += wS[w];
        excl = woff + s - v;
        if (t < rows_here) {
            rbeg[rowbase + t] = base + excl;
            rend[rowbase + t] = base + excl + v;
        }
    }
    __syncthreads();
    if (t < BROWS) cnt[t] = excl;
    __syncthreads();

    // place row-sorted into LDS staging (scattered LDS writes: cheap)
    for (int i = 0; i < iters; i++) {
        if (pkc[i] >= 0) {
            int r = pkc[i] & (BROWS - 1);
            staged[cnt[r] + rk[i]] = make_int2(pkc[i] >> BUCKET_SHIFT, wv[i]);
        }
    }
    __syncthreads();
    // fully coalesced copy-out
    for (int p = t; p < num; p += 1024)
        cw[base + p] = staged[p];
}

// ---- spmm: group-per-row; 8 rows/wave; lane = 16B chunk of its row ----
// (verified round-3/7 kernel, unchanged)
template <bool LAST>
__global__ __launch_bounds__(256) void spmm_kernel(
        const int* __restrict__ rbeg, const int* __restrict__ rend,
        const i2v* __restrict__ cw,
        const h8* __restrict__ Xin, h8* __restrict__ Xout,
        const h8* __restrict__ X0, const h8* __restrict__ X1,
        float* __restrict__ out, int nrows) {
    int lane = threadIdx.x & 63;
    int g = lane >> 3;     // which row of the wave's octet
    int l8 = lane & 7;     // 16B dim-chunk within the row
    int wv = (blockIdx.x * blockDim.x + threadIdx.x) >> 6;
    int totWaves = (gridDim.x * blockDim.x) >> 6;

    for (int base8 = wv * 8; base8 < nrows; base8 += totWaves * 8) {
        int row = base8 + g;
        bool valid = row < nrows;
        int beg = valid ? rbeg[row] : 0;
        int end = valid ? rend[row] : 0;

        f2v acc2[4];
        #pragma unroll
        for (int k = 0; k < 4; k++) acc2[k] = (f2v){0.f, 0.f};

        int e = beg;
        for (; e + 3 < end; e += 4) {
            i2v c0 = cw[e];
            i2v c1 = cw[e + 1];
            i2v c2 = cw[e + 2];
            i2v c3 = cw[e + 3];
            H8U v0, v1, v2, v3;
            v0.v = Xin[(c0.x << 3) + l8];
            v1.v = Xin[(c1.x << 3) + l8];
            v2.v = Xin[(c2.x << 3) + l8];
            v3.v = Xin[(c3.x << 3) + l8];
            f2v w0p = (f2v){__int_as_float(c0.y), __int_as_float(c0.y)};
            f2v w1p = (f2v){__int_as_float(c1.y), __int_as_float(c1.y)};
            f2v w2p = (f2v){__int_as_float(c2.y), __int_as_float(c2.y)};
            f2v w3p = (f2v){__int_as_float(c3.y), __int_as_float(c3.y)};
            #pragma unroll
            for (int k = 0; k < 4; k++) {
                acc2[k] += w0p * __builtin_convertvector(v0.p[k], f2v);
                acc2[k] += w1p * __builtin_convertvector(v1.p[k], f2v);
                acc2[k] += w2p * __builtin_convertvector(v2.p[k], f2v);
                acc2[k] += w3p * __builtin_convertvector(v3.p[k], f2v);
            }
        }
        for (; e + 1 < end; e += 2) {
            i2v c0 = cw[e];
            i2v c1 = cw[e + 1];
            H8U v0, v1;
            v0.v = Xin[(c0.x << 3) + l8];
            v1.v = Xin[(c1.x << 3) + l8];
            f2v w0p = (f2v){__int_as_float(c0.y), __int_as_float(c0.y)};
            f2v w1p = (f2v){__int_as_float(c1.y), __int_as_float(c1.y)};
            #pragma unroll
            for (int k = 0; k < 4; k++) {
                acc2[k] += w0p * __builtin_convertvector(v0.p[k], f2v);
                acc2[k] += w1p * __builtin_convertvector(v1.p[k], f2v);
            }
        }
        if (e < end) {
            i2v c0 = cw[e];
            H8U v0;
            v0.v = Xin[(c0.x << 3) + l8];
            f2v w0p = (f2v){__int_as_float(c0.y), __int_as_float(c0.y)};
            #pragma unroll
            for (int k = 0; k < 4; k++)
                acc2[k] += w0p * __builtin_convertvector(v0.p[k], f2v);
        }

        float* a = (float*)acc2;
        if (valid) {
            if (LAST) {
                h8 x0 = X0[(row << 3) + l8];
                h8 v1 = X1[(row << 3) + l8];
                h8 v2 = Xin[(row << 3) + l8];
                int base = (row << 6) + (l8 << 3);
                f4 o0, o1;
                o0.x = 0.25f * ((float)x0[0] + (float)v1[0] + (float)v2[0] + a[0]);
                o0.y = 0.25f * ((float)x0[1] + (float)v1[1] + (float)v2[1] + a[1]);
                o0.z = 0.25f * ((float)x0[2] + (float)v1[2] + (float)v2[2] + a[2]);
                o0.w = 0.25f * ((float)x0[3] + (float)v1[3] + (float)v2[3] + a[3]);
                o1.x = 0.25f * ((float)x0[4] + (float)v1[4] + (float)v2[4] + a[4]);
                o1.y = 0.25f * ((float)x0[5] + (float)v1[5] + (float)v2[5] + a[5]);
                o1.z = 0.25f * ((float)x0[6] + (float)v1[6] + (float)v2[6] + a[6]);
                o1.w = 0.25f * ((float)x0[7] + (float)v1[7] + (float)v2[7] + a[7]);
                f4* dst = (f4*)(out + base);
                dst[0] = o0;
                dst[1] = o1;
            } else {
                h8 o;
                #pragma unroll
                for (int k = 0; k < 8; k++) o[k] = (_Float16)a[k];
                Xout[(row << 3) + l8] = o;
            }
        }
    }
}

extern "C" void kernel_launch(void* const* d_in, const int* in_sizes, int n_in,
                              void* d_out, int out_size, void* d_ws, size_t ws_size,
                              hipStream_t stream) {
    const int* edge_row = (const int*)d_in[0];
    const int* edge_col = (const int*)d_in[1];
    const float* edge_w = (const float*)d_in[2];
    const float* user_emb = (const float*)d_in[3];
    const float* item_emb = (const float*)d_in[4];

    const int E = in_sizes[0];
    const int nu_elems = in_sizes[3];
    const int ni_elems = in_sizes[4];
    const int total = nu_elems + ni_elems;
    const int N = total / EMB;                           // 150000
    const int NBUCK = (N + BROWS - 1) >> BUCKET_SHIFT;   // 293

    size_t off = 0;
    auto carve = [&](size_t bytes) {
        void* p = (char*)d_ws + off;
        off += (bytes + 255) & ~(size_t)255;
        return p;
    };
    h8*    X0h     = (h8*)carve((size_t)total * 2);
    h8*    X1h     = (h8*)carve((size_t)total * 2);
    h8*    X2h     = (h8*)carve((size_t)total * 2);
    int*   rbeg    = (int*)carve((size_t)N * 4);
    int*   rend    = (int*)carve((size_t)N * 4);
    int*   cursor1 = (int*)carve((size_t)NBUCK * 4);
    int2*  tmp     = (int2*)carve((size_t)NBUCK * BCAP * 8);
    int2*  cw      = (int2*)carve((size_t)NBUCK * BCAP * 8);
    (void)ws_size;

    float* out = (float*)d_out;

    const int total8 = total / 8;
    const int s1Blocks = (E + S1_CHUNK - 1) / S1_CHUNK;
    const int convBlocks = (total8 + 1023) / 1024;

    hipMemsetAsync(cursor1, 0, (size_t)NBUCK * 4, stream);
    s1_convert<<<s1Blocks + convBlocks, 1024, 0, stream>>>(
        edge_row, edge_col, edge_w, cursor1, tmp,
        user_emb, item_emb, X0h, nu_elems, total8, E, s1Blocks);
    scatter2<<<NBUCK, 1024, 0, stream>>>(cursor1, tmp, cw, rbeg, rend, N);

    spmm_kernel<false><<<SPMM_BLOCKS, 256, 0, stream>>>(rbeg, rend, (const i2v*)cw,
                                                        X0h, X1h, nullptr, nullptr,
                                                        nullptr, N);
    spmm_kernel<false><<<SPMM_BLOCKS, 256, 0, stream>>>(rbeg, rend, (const i2v*)cw,
                                                        X1h, X2h, nullptr, nullptr,
                                                        nullptr, N);
    spmm_kernel<true><<<SPMM_BLOCKS, 256, 0, stream>>>(rbeg, rend, (const i2v*)cw,
                                                       X2h, nullptr, X0h, X1h,
                                                       out, N);
}